// Round 8
// baseline (295.292 us; speedup 1.0000x reference)
//
#include <hip/hip_runtime.h>
#include <cstdint>

// Problem constants (fixed by setup_inputs)
#define B_   4
#define N_   50000
#define K_   27
#define P_   (B_ * N_)           // 200000 points
#define L_   (P_ * K_)           // 5400000 flat entries (divisible by 64)
#define S_   130                 // per-dim encoding stride
#define PL_  (S_ * S_)           // 16900 plane stride (divisible by 4)
#define KS_  (B_ * S_ * S_ * S_) // 8788000 possible keys (divisible by 4)
#define W_   (L_ / 64)           // 84375 bitmap words
#define NBW  ((W_ + 255) / 256)  // 330 word-scan blocks
#define BIGP 0x7f7f7f7f          // empty marker (stencil adds <=26, stays < 2^31)

// table init (int4 BIGP fill) + bitmap zero, grid-stride
__global__ __launch_bounds__(256) void k_init(int4* __restrict__ T4,
                                              unsigned long long* __restrict__ bitmap) {
    const int n4 = KS_ / 4;
    int4 v = make_int4(BIGP, BIGP, BIGP, BIGP);
    for (int i = blockIdx.x * blockDim.x + threadIdx.x; i < n4; i += gridDim.x * blockDim.x)
        T4[i] = v;
    for (int i = blockIdx.x * blockDim.x + threadIdx.x; i < W_; i += gridDim.x * blockDim.x)
        bitmap[i] = 0ull;
}

// point table: P1[b, x+1, y+1, z+1] = min 32*p   (only 200k atomics)
__global__ __launch_bounds__(256) void k_ptab(const int* __restrict__ coords,
                                              const int* __restrict__ bidx,
                                              int* __restrict__ P1) {
    int p = blockIdx.x * blockDim.x + threadIdx.x;
    if (p >= P_) return;
    int b = bidx[p];
    int x = coords[3 * p + 0] + 1;
    int y = coords[3 * p + 1] + 1;
    int z = coords[3 * p + 2] + 1;
    int idx = ((b * S_ + x) * S_ + y) * S_ + z;
    atomicMin(&P1[idx], p << 5);
}

// Fused z+y min-plus stencil, one block per (b,x) plane staged in LDS.
//   z: dz=0 -> +1 ; src[z-1] -> +2 ; src[z+1] -> +0
//   y: dy=0 -> +3 ; tz[y-1]  -> +6 ; tz[y+1]  -> +0
__global__ __launch_bounds__(512) void k_zy(const int* __restrict__ src,
                                            int* __restrict__ dst) {
    __shared__ int pl[PL_];   // 67.6 KB
    __shared__ int tz[PL_];   // 67.6 KB (135 KB total)
    const int4* s4 = (const int4*)(src + (size_t)blockIdx.x * PL_);
    int4* d4       = (int4*)(dst + (size_t)blockIdx.x * PL_);
    int4* pl4      = (int4*)pl;
    for (int i = threadIdx.x; i < PL_ / 4; i += 512) pl4[i] = s4[i];
    __syncthreads();
    for (int i = threadIdx.x; i < PL_; i += 512) {
        int z = i % S_;
        int v = pl[i] + 1;
        if (z > 0)      v = min(v, pl[i - 1] + 2);
        if (z < S_ - 1) v = min(v, pl[i + 1]);
        tz[i] = v;
    }
    __syncthreads();
    for (int i = threadIdx.x; i < PL_ / 4; i += 512) {
        int4 o;
        int base = 4 * i;
        #pragma unroll
        for (int j = 0; j < 4; ++j) {
            int idx = base + j;
            int y = idx / S_;
            int v = tz[idx] + 3;
            if (y > 0)      v = min(v, tz[idx - S_] + 6);
            if (y < S_ - 1) v = min(v, tz[idx + S_]);
            ((int*)&o)[j] = v;
        }
        d4[i] = o;
    }
}

// x min-plus stencil (int4) + first-occurrence bitmap bits.
// Each finite cell value m32 = (p<<5)|k IS the first-occurrence l of that cell
// (cells are disjoint in l), so we set bit l=(m32>>5)*27+(m32&31) directly.
// atomicOr targets the 675KB bitmap -> L2-resident, ~num_unique ops.
__global__ __launch_bounds__(256) void k_x(const int4* __restrict__ src,
                                           int4* __restrict__ dst,
                                           unsigned long long* __restrict__ bitmap) {
    const int n4 = KS_ / 4;
    int i = blockIdx.x * blockDim.x + threadIdx.x;
    if (i >= n4) return;
    int x = (i / (PL_ / 4)) % S_;
    int4 c = src[i];
    int4 v = make_int4(c.x + 9, c.y + 9, c.z + 9, c.w + 9);
    if (x > 0) {
        int4 m = src[i - PL_ / 4];
        v.x = min(v.x, m.x + 18); v.y = min(v.y, m.y + 18);
        v.z = min(v.z, m.z + 18); v.w = min(v.w, m.w + 18);
    }
    if (x < S_ - 1) {
        int4 pp = src[i + PL_ / 4];
        v.x = min(v.x, pp.x); v.y = min(v.y, pp.y);
        v.z = min(v.z, pp.z); v.w = min(v.w, pp.w);
    }
    dst[i] = v;
    #pragma unroll
    for (int j = 0; j < 4; ++j) {
        int m32 = ((int*)&v)[j];
        if (m32 < BIGP) {
            int l = (m32 >> 5) * K_ + (m32 & 31);
            atomicOr(&bitmap[l >> 6], 1ull << (l & 63));
        }
    }
}

// per-word popcount + per-block exclusive scan over 84375 words
__global__ __launch_bounds__(256) void k_scan_words(const unsigned long long* __restrict__ bitmap,
                                                    int* __restrict__ wpre,
                                                    int* __restrict__ bsum) {
    __shared__ int sh[256];
    int w = blockIdx.x * 256 + threadIdx.x;
    int c = (w < W_) ? __popcll(bitmap[w]) : 0;
    sh[threadIdx.x] = c;
    __syncthreads();
    for (int off = 1; off < 256; off <<= 1) {
        int t = (threadIdx.x >= off) ? sh[threadIdx.x - off] : 0;
        __syncthreads();
        sh[threadIdx.x] += t;
        __syncthreads();
    }
    if (w < W_) wpre[w] = sh[threadIdx.x] - c;        // exclusive within block
    if (threadIdx.x == 255) bsum[blockIdx.x] = sh[255];
}

// single-block exclusive scan over the 330 block sums; emits num_unique
__global__ __launch_bounds__(512) void k_scan_block(int* __restrict__ bsum,
                                                    int* __restrict__ num_unique_out) {
    __shared__ int sh[512];
    int i = threadIdx.x;
    int v = (i < NBW) ? bsum[i] : 0;
    sh[i] = v;
    __syncthreads();
    for (int off = 1; off < 512; off <<= 1) {
        int t = (i >= off) ? sh[i - off] : 0;
        __syncthreads();
        sh[i] += t;
        __syncthreads();
    }
    if (i < NBW) bsum[i] = sh[i] - v;                 // global exclusive prefix
    if (i == 0) num_unique_out[0] = sh[511];
}

// THE single random pass: gather M[cell(l)], rank via bitmap popcount
// (bitmap+wpre ~1.3MB, L2-resident), all outputs written here.
__global__ __launch_bounds__(256) void k_finalize(const int* __restrict__ coords,
                                                  const int* __restrict__ bidx,
                                                  const int* __restrict__ koffs,
                                                  const int* __restrict__ M,
                                                  const unsigned long long* __restrict__ bitmap,
                                                  const int* __restrict__ wpre,
                                                  const int* __restrict__ bsum,
                                                  const int* __restrict__ numuniq,
                                                  int* __restrict__ out0,
                                                  int* __restrict__ out1,
                                                  int* __restrict__ out2,
                                                  int* __restrict__ outkey) {
    int l = blockIdx.x * blockDim.x + threadIdx.x;
    if (l >= L_) return;
    int p = l / K_;
    int k = l - p * K_;
    out0[l] = p - (p / N_) * N_;   // n
    out2[l] = k;
    int b = bidx[p];
    int cx = coords[3 * p + 0] + koffs[3 * k + 0] + 1;
    int cy = coords[3 * p + 1] + koffs[3 * k + 1] + 1;
    int cz = coords[3 * p + 2] + koffs[3 * k + 2] + 1;
    int idx = ((b * S_ + cx) * S_ + cy) * S_ + cz;
    int m32 = M[idx];
    int m = (m32 >> 5) * K_ + (m32 & 31);
    int w = m >> 6;
    unsigned long long word = bitmap[w];
    unsigned long long mask = (1ull << (m & 63)) - 1ull;
    int rank = wpre[w] + bsum[w >> 8] + (int)__popcll(word & mask);
    out1[l] = rank;
    if (m == l) {
        outkey[3 * rank + 0] = cx - 1;
        outkey[3 * rank + 1] = cy - 1;
        outkey[3 * rank + 2] = cz - 1;
    }
    if (l >= numuniq[0]) {            // tail row l -> -1 (disjoint from valid rows)
        outkey[3 * l + 0] = -1;
        outkey[3 * l + 1] = -1;
        outkey[3 * l + 2] = -1;
    }
}

extern "C" void kernel_launch(void* const* d_in, const int* in_sizes, int n_in,
                              void* d_out, int out_size, void* d_ws, size_t ws_size,
                              hipStream_t stream) {
    const int* coords = (const int*)d_in[0];   // [B,N,3] int32
    const int* bidx   = (const int*)d_in[1];   // [B,N]   int32
    const int* koffs  = (const int*)d_in[2];   // [27,3]  int32

    int* out      = (int*)d_out;
    int* out0     = out;            // input_idx      [L]
    int* out1     = out + L_;       // output_idx     [L]
    int* out2     = out + 2 * L_;   // rel_pos_idx    [L]
    int* outkey   = out + 3 * L_;   // output_key     [L,3]
    int* numuniq  = out + 6 * L_;   // num_unique     [1]

    // ws (~36.2 MB): P1 | bitmap | wpre | bsum
    int* P1 = (int*)d_ws;                                         // KS_ ints
    unsigned long long* bitmap = (unsigned long long*)(P1 + KS_); // W_ u64 (8B aligned)
    int* wpre = (int*)(bitmap + W_);                              // W_ ints
    int* bsum = wpre + W_;                                        // NBW ints

    // stencil ping-pong scratch A lives in the (not-yet-written) outkey region:
    // KS_ ints <= 3*L_ ints; fully consumed by k_x before k_finalize writes outkey.
    int* A = outkey;

    k_init       <<<2048, 256, 0, stream>>>((int4*)P1, bitmap);
    k_ptab       <<<(P_ + 255) / 256, 256, 0, stream>>>(coords, bidx, P1);
    k_zy         <<<B_ * S_, 512, 0, stream>>>(P1, A);                      // P1 -> A
    k_x          <<<(KS_ / 4 + 255) / 256, 256, 0, stream>>>((const int4*)A, (int4*)P1, bitmap);
    k_scan_words <<<NBW, 256, 0, stream>>>(bitmap, wpre, bsum);
    k_scan_block <<<1, 512, 0, stream>>>(bsum, numuniq);
    k_finalize   <<<(L_ + 255) / 256, 256, 0, stream>>>(coords, bidx, koffs, P1,
                                                        bitmap, wpre, bsum, numuniq,
                                                        out0, out1, out2, outkey);
}

// Round 9
// 143.757 us; speedup vs baseline: 2.0541x; 2.0541x over previous
//
#include <hip/hip_runtime.h>
#include <cstdint>

// Problem constants (fixed by setup_inputs)
#define B_   4
#define N_   50000
#define K_   27
#define P_   (B_ * N_)           // 200000 points
#define L_   (P_ * K_)           // 5400000 flat entries (64 | L_)
#define S_   130                 // per-dim encoding stride
#define PL_  (S_ * S_)           // 16900 plane stride (divisible by 4)
#define KS_  (B_ * S_ * S_ * S_) // 8788000 possible keys (divisible by 4)
#define W_   (L_ / 64)           // 84375 bitmap words
#define NBW  ((W_ + 255) / 256)  // 330 word-scan blocks
#define BIGP 0x7f7f7f7f          // empty marker (stencil adds <=26, stays < 2^31)

// table init (int4 BIGP fill); bitmap needs no init (fully ballot-written)
__global__ __launch_bounds__(256) void k_init(int4* __restrict__ T4) {
    const int n4 = KS_ / 4;
    int4 v = make_int4(BIGP, BIGP, BIGP, BIGP);
    for (int i = blockIdx.x * blockDim.x + threadIdx.x; i < n4; i += gridDim.x * blockDim.x)
        T4[i] = v;
}

// point table: P1[cell(p)] = min 32*p  (200k atomics, uncontended-ish)
// also stores each point's cell base index for the gather pass.
__global__ __launch_bounds__(256) void k_ptab(const int* __restrict__ coords,
                                              const int* __restrict__ bidx,
                                              int* __restrict__ P1,
                                              int* __restrict__ bpt) {
    int p = blockIdx.x * blockDim.x + threadIdx.x;
    if (p >= P_) return;
    int b = bidx[p];
    int x = coords[3 * p + 0] + 1;
    int y = coords[3 * p + 1] + 1;
    int z = coords[3 * p + 2] + 1;
    int idx = ((b * S_ + x) * S_ + y) * S_ + z;
    bpt[p] = idx;
    atomicMin(&P1[idx], p << 5);
}

// Fused z+y min-plus stencil, one block per (b,x) plane staged in LDS.
//   z: center +1 ; from z-1 +2 ; from z+1 +0
//   y: center +3 ; from y-1 +6 ; from y+1 +0
__global__ __launch_bounds__(512) void k_zy(const int* __restrict__ src,
                                            int* __restrict__ dst) {
    __shared__ int pl[PL_];   // 67.6 KB
    __shared__ int tz[PL_];   // 67.6 KB (135 KB total)
    const int4* s4 = (const int4*)(src + (size_t)blockIdx.x * PL_);
    int4* d4       = (int4*)(dst + (size_t)blockIdx.x * PL_);
    int4* pl4      = (int4*)pl;
    for (int i = threadIdx.x; i < PL_ / 4; i += 512) pl4[i] = s4[i];
    __syncthreads();
    for (int i = threadIdx.x; i < PL_; i += 512) {
        int z = i % S_;
        int v = pl[i] + 1;
        if (z > 0)      v = min(v, pl[i - 1] + 2);
        if (z < S_ - 1) v = min(v, pl[i + 1]);
        tz[i] = v;
    }
    __syncthreads();
    for (int i = threadIdx.x; i < PL_ / 4; i += 512) {
        int4 o;
        int base = 4 * i;
        #pragma unroll
        for (int j = 0; j < 4; ++j) {
            int idx = base + j;
            int y = idx / S_;
            int v = tz[idx] + 3;
            if (y > 0)      v = min(v, tz[idx - S_] + 6);
            if (y < S_ - 1) v = min(v, tz[idx + S_]);
            ((int*)&o)[j] = v;
        }
        d4[i] = o;
    }
}

// x min-plus stencil, int4-vectorized, NO atomics (R8 post-mortem).
__global__ __launch_bounds__(256) void k_x(const int4* __restrict__ src,
                                           int4* __restrict__ dst) {
    const int n4 = KS_ / 4;
    int i = blockIdx.x * blockDim.x + threadIdx.x;
    if (i >= n4) return;
    int x = (i / (PL_ / 4)) % S_;
    int4 c = src[i];
    int4 v = make_int4(c.x + 9, c.y + 9, c.z + 9, c.w + 9);
    if (x > 0) {
        int4 m = src[i - PL_ / 4];
        v.x = min(v.x, m.x + 18); v.y = min(v.y, m.y + 18);
        v.z = min(v.z, m.z + 18); v.w = min(v.w, m.w + 18);
    }
    if (x < S_ - 1) {
        int4 pp = src[i + PL_ / 4];
        v.x = min(v.x, pp.x); v.y = min(v.y, pp.y);
        v.z = min(v.z, pp.z); v.w = min(v.w, pp.w);
    }
    dst[i] = v;
}

// THE random pass: idx = bpt[p] + klin(k) (pure arithmetic k-offset),
// gather m32, ballot -> bitmap, store m32 to mArr; out0/out2 fills ride
// under the fetch-bound gather.
__global__ __launch_bounds__(256) void k_gather(const int* __restrict__ bpt,
                                                const int* __restrict__ M,
                                                int* __restrict__ mArr,
                                                unsigned long long* __restrict__ bitmap,
                                                int* __restrict__ out0,
                                                int* __restrict__ out2) {
    int l = blockIdx.x * blockDim.x + threadIdx.x;
    if (l >= L_) return;
    int p = l / K_;
    int k = l - p * K_;
    out0[l] = p - (p / N_) * N_;   // n
    out2[l] = k;
    int dx = k / 9, dy = (k / 3) % 3, dz = k - (k / 3) * 3;
    int idx = bpt[p] + (dx - 1) * PL_ + (dy - 1) * S_ + (dz - 1);
    int m32 = M[idx];
    mArr[l] = m32;
    unsigned long long bal = __ballot(m32 == ((p << 5) | k));
    if ((threadIdx.x & 63) == 0) bitmap[l >> 6] = bal;
}

// per-word popcount + per-block exclusive scan over 84375 words
__global__ __launch_bounds__(256) void k_scan_words(const unsigned long long* __restrict__ bitmap,
                                                    int* __restrict__ wpre,
                                                    int* __restrict__ bsum) {
    __shared__ int sh[256];
    int w = blockIdx.x * 256 + threadIdx.x;
    int c = (w < W_) ? __popcll(bitmap[w]) : 0;
    sh[threadIdx.x] = c;
    __syncthreads();
    for (int off = 1; off < 256; off <<= 1) {
        int t = (threadIdx.x >= off) ? sh[threadIdx.x - off] : 0;
        __syncthreads();
        sh[threadIdx.x] += t;
        __syncthreads();
    }
    if (w < W_) wpre[w] = sh[threadIdx.x] - c;        // exclusive within block
    if (threadIdx.x == 255) bsum[blockIdx.x] = sh[255];
}

// single-block exclusive scan over the 330 block sums; emits num_unique
__global__ __launch_bounds__(512) void k_scan_block(int* __restrict__ bsum,
                                                    int* __restrict__ num_unique_out) {
    __shared__ int sh[512];
    int i = threadIdx.x;
    int v = (i < NBW) ? bsum[i] : 0;
    sh[i] = v;
    __syncthreads();
    for (int off = 1; off < 512; off <<= 1) {
        int t = (i >= off) ? sh[i - off] : 0;
        __syncthreads();
        sh[i] += t;
        __syncthreads();
    }
    if (i < NBW) bsum[i] = sh[i] - v;                 // global exclusive prefix
    if (i == 0) num_unique_out[0] = sh[511];
}

// rank via bitmap popcount (bitmap+wpre ~1.3MB, L2-resident); valid outkey
// rows written once; tail rows (>= num_unique) written -1 here (disjoint).
__global__ __launch_bounds__(256) void k_finalize(const int* __restrict__ coords,
                                                  const int* __restrict__ koffs,
                                                  const unsigned long long* __restrict__ bitmap,
                                                  const int* __restrict__ wpre,
                                                  const int* __restrict__ bsum,
                                                  const int* __restrict__ numuniq,
                                                  int* __restrict__ out1,   // holds m32, becomes output_idx
                                                  int* __restrict__ outkey) {
    int l = blockIdx.x * blockDim.x + threadIdx.x;
    if (l >= L_) return;
    int m32 = out1[l];
    int m = (m32 >> 5) * K_ + (m32 & 31);
    int w = m >> 6;
    unsigned long long word = bitmap[w];
    unsigned long long mask = (1ull << (m & 63)) - 1ull;
    int rank = wpre[w] + bsum[w >> 8] + (int)__popcll(word & mask);
    out1[l] = rank;
    if (m == l) {
        int p = l / K_;
        int k = l - p * K_;
        outkey[3 * rank + 0] = coords[3 * p + 0] + koffs[3 * k + 0];
        outkey[3 * rank + 1] = coords[3 * p + 1] + koffs[3 * k + 1];
        outkey[3 * rank + 2] = coords[3 * p + 2] + koffs[3 * k + 2];
    }
    if (l >= numuniq[0]) {
        outkey[3 * l + 0] = -1;
        outkey[3 * l + 1] = -1;
        outkey[3 * l + 2] = -1;
    }
}

extern "C" void kernel_launch(void* const* d_in, const int* in_sizes, int n_in,
                              void* d_out, int out_size, void* d_ws, size_t ws_size,
                              hipStream_t stream) {
    const int* coords = (const int*)d_in[0];   // [B,N,3] int32
    const int* bidx   = (const int*)d_in[1];   // [B,N]   int32
    const int* koffs  = (const int*)d_in[2];   // [27,3]  int32

    int* out      = (int*)d_out;
    int* out0     = out;            // input_idx      [L]
    int* out1     = out + L_;       // output_idx     [L] (holds m32 first)
    int* out2     = out + 2 * L_;   // rel_pos_idx    [L]
    int* outkey   = out + 3 * L_;   // output_key     [L,3]
    int* numuniq  = out + 6 * L_;   // num_unique     [1]

    // ws (~37 MB): P1 | bitmap | wpre | bsum | bpt
    int* P1 = (int*)d_ws;                                         // KS_ ints
    unsigned long long* bitmap = (unsigned long long*)(P1 + KS_); // W_ u64 (8B aligned)
    int* wpre = (int*)(bitmap + W_);                              // W_ ints
    int* bsum = wpre + W_;                                        // NBW ints
    int* bpt  = bsum + NBW;                                       // P_ ints

    // stencil ping-pong scratch A in the (not-yet-written) outkey region:
    // KS_ ints <= 3*L_ ints; fully consumed by k_x before k_finalize writes outkey.
    int* A = outkey;

    k_init       <<<2048, 256, 0, stream>>>((int4*)P1);
    k_ptab       <<<(P_ + 255) / 256, 256, 0, stream>>>(coords, bidx, P1, bpt);
    k_zy         <<<B_ * S_, 512, 0, stream>>>(P1, A);                      // P1 -> A
    k_x          <<<(KS_ / 4 + 255) / 256, 256, 0, stream>>>((const int4*)A, (int4*)P1);
    k_gather     <<<(L_ + 255) / 256, 256, 0, stream>>>(bpt, P1, out1, bitmap, out0, out2);
    k_scan_words <<<NBW, 256, 0, stream>>>(bitmap, wpre, bsum);
    k_scan_block <<<1, 512, 0, stream>>>(bsum, numuniq);
    k_finalize   <<<(L_ + 255) / 256, 256, 0, stream>>>(coords, koffs, bitmap, wpre, bsum,
                                                        numuniq, out1, outkey);
}